// Round 16
// baseline (1742.167 us; speedup 1.0000x reference)
//
#include <hip/hip_runtime.h>

typedef unsigned int uint;
typedef unsigned long long u64;
typedef unsigned short ushort;
typedef _Float16 f16;
typedef _Float16 f16x2 __attribute__((ext_vector_type(2)));
typedef _Float16 f16x8 __attribute__((ext_vector_type(8)));
typedef float f32x4 __attribute__((ext_vector_type(4)));

#define N_TYPES 10000
#define HID 256
#define G4 1024
#define BATCH 32
#define SEQ 1024

// ---------------- K1: path table: path[n][h] = sum_d cumw_d * emb[anc[n,d]][h]
__global__ void k_path(const int* __restrict__ anc, const float* __restrict__ weight,
                       const float* __restrict__ emb, int D, f16* __restrict__ path) {
  int n = blockIdx.x;
  int h = threadIdx.x;
  float acc = 0.f, cw = 1.f;
  for (int d = 0; d < D; ++d) {
    int a = anc[n * D + d];
    if (a < 0) break;
    acc += cw * emb[a * HID + h];
    cw *= weight[a];
  }
  path[n * HID + h] = (f16)acc;
}

// ---------------- K0: convert W_ih -> f16, W_hh -> transposed packed f16 pairs, bias = b_ih+b_hh
// whh_t layout: [128 kpair][1024 row] u32 (pair = f16 k, k+1 of row)
__global__ void k_conv(const float* __restrict__ wih, const float* __restrict__ whh,
                       const float* __restrict__ bih, const float* __restrict__ bhh,
                       f16* __restrict__ wih_h, uint* __restrict__ whh_t,
                       float* __restrict__ bias) {
  int i = blockIdx.x * 256 + threadIdx.x;   // 262144 threads
  wih_h[i] = (f16)wih[i];
  if (i < G4 * 128) {
    int row = i >> 7, p = i & 127;
    f16x2 v;
    v.x = (f16)whh[row * HID + 2 * p];
    v.y = (f16)whh[row * HID + 2 * p + 1];
    whh_t[p * G4 + row] = __builtin_bit_cast(uint, v);
  }
  if (i < G4) bias[i] = bih[i] + bhh[i];
}

// ---------------- K2: proj[n][dim][gate] = path[n]@W_ih^T + b (gate-packed epilogue)
#define BM 128
#define BN 128
#define BK 64
#define LPAD 72
__global__ __launch_bounds__(256) void k_gemm(const f16* __restrict__ A,
                                              const f16* __restrict__ Bw,
                                              const float* __restrict__ bias,
                                              f16* __restrict__ C) {
  __shared__ f16 sA[BM][LPAD];
  __shared__ f16 sB[BN][LPAD];
  int m0 = blockIdx.x * BM, n0 = blockIdx.y * BN;
  int tid = threadIdx.x;
  int wid = tid >> 6, lane = tid & 63;
  int wm = wid & 1, wn = wid >> 1;
  f32x4 acc[4][4] = {};
  for (int k0 = 0; k0 < 256; k0 += BK) {
    __syncthreads();
    int r = tid >> 3, kc = (tid & 7) * 8;
    for (int i = 0; i < 4; ++i) {
      int row = r + 32 * i;
      int gm = m0 + row;
      uint4 va = make_uint4(0u, 0u, 0u, 0u);
      if (gm < N_TYPES) va = *(const uint4*)&A[gm * 256 + k0 + kc];
      *(uint4*)&sA[row][kc] = va;
      uint4 vb = *(const uint4*)&Bw[(n0 + row) * 256 + k0 + kc];
      *(uint4*)&sB[row][kc] = vb;
    }
    __syncthreads();
#pragma unroll
    for (int ks = 0; ks < 2; ++ks) {
      f16x8 af[4], bf[4];
      int kk = ks * 32 + (lane >> 4) * 8;
#pragma unroll
      for (int mt = 0; mt < 4; ++mt)
        af[mt] = *(const f16x8*)&sA[wm * 64 + mt * 16 + (lane & 15)][kk];
#pragma unroll
      for (int nt = 0; nt < 4; ++nt)
        bf[nt] = *(const f16x8*)&sB[wn * 64 + nt * 16 + (lane & 15)][kk];
#pragma unroll
      for (int mt = 0; mt < 4; ++mt)
#pragma unroll
        for (int nt = 0; nt < 4; ++nt)
          acc[mt][nt] = __builtin_amdgcn_mfma_f32_16x16x32_f16(af[mt], bf[nt], acc[mt][nt], 0, 0, 0);
    }
  }
#pragma unroll
  for (int mt = 0; mt < 4; ++mt)
#pragma unroll
    for (int nt = 0; nt < 4; ++nt)
#pragma unroll
      for (int qq = 0; qq < 4; ++qq) {
        int row = m0 + wm * 64 + mt * 16 + (lane >> 4) * 4 + qq;
        int col = n0 + wn * 64 + nt * 16 + (lane & 15);
        int dim = col & 255, g = col >> 8;
        if (row < N_TYPES)
          C[row * G4 + dim * 4 + g] = (f16)(acc[mt][nt][qq] + bias[col]);
      }
}

// ---------------- K3: LSTM recurrence, v16 = R15 structure, BARRIER-FREE steady loop.
// Base: 256 WGs x 512 thr, bid=q*32+b; WG q owns dims [q*32,+32) x 4 gates = 128
// rows, k-split over wave-pairs (kq=v>>1); per-thread w[32]; tagged {f16x2,step}
// u64 agent-relaxed fabric; wave 6 polls+relays kq=3; wave 7 = vmem-free finale.
//
// R15 post-mortem: __syncthreads costs max-of-8 arrival PLUS per-wave vmcnt(0)
// drains (publish/out/x acks) that the finale does not need -- it only needs the
// 8 pl LDS writes. Fix: replace the in-loop barrier with tagged LDS flags:
//  * each wave: write pl -> release-store pflag[par][v]=step+1 (workgroup scope,
//    LDS: lgkmcnt-only, NO vmem drain) -> proceed straight to step t+1's poll.
//  * wave 7: acquire-spin on pflag[par][0..6] (~40cy cadence), read pl, finale.
// Safety w/o barriers: finale(t+1) of ANY WG transitively requires finale(t) of
// ALL 8 WGs (4-quarter fan-in covers producers 0..7), so pl/hrelay/hglob slot
// reuse at t+2 always post-dates every step-t read (same closure as R5's proof).
// Monotone step tags kill ABA on flags.
__device__ __forceinline__ float dot2(uint wp, uint hp, float acc) {
#if __has_builtin(__builtin_amdgcn_fdot2)
  return __builtin_amdgcn_fdot2(__builtin_bit_cast(f16x2, wp),
                                __builtin_bit_cast(f16x2, hp), acc, false);
#else
  f16x2 a = __builtin_bit_cast(f16x2, wp);
  f16x2 b = __builtin_bit_cast(f16x2, hp);
  return acc + (float)a.x * (float)b.x + (float)a.y * (float)b.y;
#endif
}

__device__ __forceinline__ float sigm(float v) { return 1.f / (1.f + __expf(-v)); }
__device__ __forceinline__ float tanh_(float v) { return 1.f - 2.f / (__expf(2.f * v) + 1.f); }
__device__ __forceinline__ float f16u(ushort u) { return (float)__builtin_bit_cast(f16, u); }

__global__ __launch_bounds__(512, 2)
void k_lstm(const int* __restrict__ evs,
            const f16* __restrict__ proj,
            const uint* __restrict__ whh_t,
            u64* hglob,                 // [32 batch][2 slot][128 pair] tagged words
            float* __restrict__ out) {
  int bid = blockIdx.x;
  int b = bid & 31, q = bid >> 5;      // 8 WGs of batch b share bid%8 -> same XCD
  int t = threadIdx.x;
  int v = t >> 6, l = t & 63;
  int kq = v >> 1;                     // k-quarter, wave-uniform
  int rid = (v & 1) * 64 + l;          // local gate-row 0..127
  int rowg = (rid >> 5) * 256 + q * 32 + (rid & 31);   // global gate-row

  __shared__ float pl[2][4][128];      // partials [parity][kq][rid]
  __shared__ uint hrelay[2][32];       // wave6 -> wave7 kq=3 payload relay
  __shared__ uint hflag[2];            // relay flags (tag = step)
  __shared__ uint pflag[2][8];         // per-wave partial-done flags (tag = step+1)

  if (t < 2) hflag[t] = 0;
  if (t < 16) pflag[t >> 3][t & 7] = 0;

  uint w[32];
#pragma unroll
  for (int i = 0; i < 32; ++i) w[i] = whh_t[(kq * 32 + i) * G4 + rowg];

  u64* hb = hglob + b * 256;           // [2][128]
  const int* ev = evs + b * SEQ;

  // finale wave = wave 7, lanes 0..31: x (gate-packed) one step ahead
  float x0 = 0.f, x1 = 0.f, x2 = 0.f, x3 = 0.f;
  if (v == 7 && l < 32) {
    ushort4 xv = *(const ushort4*)(proj + (long)ev[0] * G4 + (q * 32 + l) * 4);
    x0 = f16u(xv.x); x1 = f16u(xv.y); x2 = f16u(xv.z); x3 = f16u(xv.w);
  }

  __syncthreads();                     // one-time: flag init + w loads visible

  float c = 0.f;

  for (int step = 0; step < SEQ; ++step) {
    int parp = step & 1;               // pl / pflag parity
    int parh = (step - 1) & 1;         // h / hrelay parity being consumed
    uint ptag = (uint)(step + 1);

    if (v < 7) {
      // (1a) waves 0..6: vmem poll on lanes 32..63 (these lanes never store)
      int h0 = 0;
      if (step > 0 && l >= 32) {
        const u64* src = hb + parh * 128 + kq * 32 + (l - 32);
        u64 val;
        do {
          val = __hip_atomic_load(src, __ATOMIC_RELAXED, __HIP_MEMORY_SCOPE_AGENT);
        } while ((uint)(val >> 32) != (uint)step);
        h0 = (int)(uint)val;
      }
      // wave 6 relays kq=3 payloads to wave 7 ASAP (release = lgkmcnt-only)
      if (v == 6 && step > 0) {
        if (l >= 32) hrelay[parh][l - 32] = (uint)h0;
        if (l == 32)
          __hip_atomic_store(&hflag[parh], (uint)step,
                             __ATOMIC_RELEASE, __HIP_MEMORY_SCOPE_WORKGROUP);
      }
      // (2a) matvec via readlane broadcast from lanes 32..63
      float a0 = 0.f, a1 = 0.f, a2 = 0.f, a3 = 0.f;
#pragma unroll
      for (int i = 0; i < 32; i += 4) {
        a0 = dot2(w[i + 0], (uint)__builtin_amdgcn_readlane(h0, 32 + i + 0), a0);
        a1 = dot2(w[i + 1], (uint)__builtin_amdgcn_readlane(h0, 32 + i + 1), a1);
        a2 = dot2(w[i + 2], (uint)__builtin_amdgcn_readlane(h0, 32 + i + 2), a2);
        a3 = dot2(w[i + 3], (uint)__builtin_amdgcn_readlane(h0, 32 + i + 3), a3);
      }
      pl[parp][kq][rid] = (a0 + a1) + (a2 + a3);
      // release partial-done flag (orders the pl write; NO vmem drain), run ahead
      if (l == 0)
        __hip_atomic_store(&pflag[parp][v], ptag,
                           __ATOMIC_RELEASE, __HIP_MEMORY_SCOPE_WORKGROUP);
    } else {
      // (1b) wave 7: LDS-only path. Spin relay flag, matvec kq=3 rows 64..127.
      float a0 = 0.f, a1 = 0.f, a2 = 0.f, a3 = 0.f;
      if (step > 0) {
        while (__hip_atomic_load(&hflag[parh], __ATOMIC_ACQUIRE,
                                 __HIP_MEMORY_SCOPE_WORKGROUP) != (uint)step) {}
        const uint4* hp4 = (const uint4*)&hrelay[parh][0];
#pragma unroll
        for (int i4 = 0; i4 < 8; ++i4) {
          uint4 h4 = hp4[i4];          // wave-uniform -> broadcast, conflict-free
          a0 = dot2(w[4 * i4 + 0], h4.x, a0);
          a1 = dot2(w[4 * i4 + 1], h4.y, a1);
          a2 = dot2(w[4 * i4 + 2], h4.z, a2);
          a3 = dot2(w[4 * i4 + 3], h4.w, a3);
        }
      }
      pl[parp][3][64 + l] = (a0 + a1) + (a2 + a3);   // wave 7's own slice

      // (2b) spin the 7 partial flags (acquire, ~40cy cadence; no vmem involved)
      bool done;
      do {
        uint fl = ptag;
        if (l < 7)
          fl = __hip_atomic_load(&pflag[parp][l], __ATOMIC_ACQUIRE,
                                 __HIP_MEMORY_SCOPE_WORKGROUP);
        done = __all(fl == ptag);
      } while (!done);

      // (3) finale on lanes 0..31: reduce + activations + publish + out + x-pf
      if (l < 32) {
        const float (*pp)[128] = pl[parp];
        float s0 = (pp[0][l]      + pp[1][l])      + (pp[2][l]      + pp[3][l])      + x0;
        float s1 = (pp[0][32 + l] + pp[1][32 + l]) + (pp[2][32 + l] + pp[3][32 + l]) + x1;
        float s2 = (pp[0][64 + l] + pp[1][64 + l]) + (pp[2][64 + l] + pp[3][64 + l]) + x2;
        float s3 = (pp[0][96 + l] + pp[1][96 + l]) + (pp[2][96 + l] + pp[3][96 + l]) + x3;
        float iv = sigm(s0), fv = sigm(s1), gv = tanh_(s2), ov = sigm(s3);
        c = fv * c + iv * gv;
        float hval = ov * tanh_(c);
        float hA = __shfl(hval, 2 * (l & 15));
        float hB = __shfl(hval, 2 * (l & 15) + 1);
        if (l < 16) {                  // publish FIRST (critical path)
          f16x2 pk; pk.x = (f16)hA; pk.y = (f16)hB;
          uint pku = __builtin_bit_cast(uint, pk);
          u64 val = (u64)pku | ((u64)(uint)(step + 1) << 32);
          __hip_atomic_store(hb + parp * 128 + q * 16 + l, val,
                             __ATOMIC_RELAXED, __HIP_MEMORY_SCOPE_AGENT);
        }
        out[(step * BATCH + b) * HID + q * 32 + l] = hval;
        if (step + 1 < SEQ) {          // x-prefetch; acks retire under next spins
          ushort4 xv = *(const ushort4*)(proj + (long)ev[step + 1] * G4 + (q * 32 + l) * 4);
          x0 = f16u(xv.x); x1 = f16u(xv.y); x2 = f16u(xv.z); x3 = f16u(xv.w);
        }
      }
    }
    // Slot-reuse safety (no barrier): finale(t+1) of ANY WG requires h(t+1) from
    // finales(t) of ALL 8 WGs (4 quarters x 2 producers). Hence any pl/hrelay/
    // pflag/hglob rewrite at t+2 post-dates every step-t read. Tags are monotone.
  }
}

extern "C" void kernel_launch(void* const* d_in, const int* in_sizes, int n_in,
                              void* d_out, int out_size, void* d_ws, size_t ws_size,
                              hipStream_t stream) {
  (void)n_in; (void)out_size; (void)ws_size;
  const int* evs = (const int*)d_in[0];
  const int* anc = (const int*)d_in[1];
  const float* weight = (const float*)d_in[2];
  const float* emb = (const float*)d_in[3];
  const float* wih = (const float*)d_in[4];
  const float* whh = (const float*)d_in[5];
  const float* bih = (const float*)d_in[6];
  const float* bhh = (const float*)d_in[7];
  int D = in_sizes[1] / N_TYPES;

  char* ws = (char*)d_ws;
  f16* path = (f16*)(ws);                       // 10000*256*2 = 5,120,000 (dead after k_gemm)
  f16* wih_h = (f16*)(ws + 5242880);            // 524,288
  uint* whh_t = (uint*)(ws + 5767168);          // 524,288
  float* bias = (float*)(ws + 6291456);         // 4,096
  f16* proj = (f16*)(ws + 6295552);             // 10000*1024*2 = 20,480,000 (gate-packed)
  u64* hglob = (u64*)(ws + 26775552);           // 32*2*128*8 = 65,536
  float* out = (float*)d_out;

  k_conv<<<1024, 256, 0, stream>>>(wih, whh, bih, bhh, wih_h, whh_t, bias);
  k_path<<<N_TYPES, 256, 0, stream>>>(anc, weight, emb, D, path);
  k_gemm<<<dim3(79, 8), 256, 0, stream>>>(path, wih_h, bias, proj);
  hipMemsetAsync(hglob, 0, 32 * 2 * 128 * 8, stream);   // zero tags (replay-safe)
  k_lstm<<<256, 512, 0, stream>>>(evs, proj, whh_t, hglob, out);
}

// Round 17
// 1603.116 us; speedup vs baseline: 1.0867x; 1.0867x over previous
//
#include <hip/hip_runtime.h>

typedef unsigned int uint;
typedef unsigned long long u64;
typedef unsigned short ushort;
typedef _Float16 f16;
typedef _Float16 f16x2 __attribute__((ext_vector_type(2)));
typedef _Float16 f16x8 __attribute__((ext_vector_type(8)));
typedef float f32x4 __attribute__((ext_vector_type(4)));

#define N_TYPES 10000
#define HID 256
#define G4 1024
#define BATCH 32
#define SEQ 1024

// ---------------- K1: path table: path[n][h] = sum_d cumw_d * emb[anc[n,d]][h]
__global__ void k_path(const int* __restrict__ anc, const float* __restrict__ weight,
                       const float* __restrict__ emb, int D, f16* __restrict__ path) {
  int n = blockIdx.x;
  int h = threadIdx.x;
  float acc = 0.f, cw = 1.f;
  for (int d = 0; d < D; ++d) {
    int a = anc[n * D + d];
    if (a < 0) break;
    acc += cw * emb[a * HID + h];
    cw *= weight[a];
  }
  path[n * HID + h] = (f16)acc;
}

// ---------------- K0: convert W_ih -> f16, W_hh -> transposed packed f16 pairs, bias = b_ih+b_hh
// whh_t layout: [128 kpair][1024 row] u32 (pair = f16 k, k+1 of row)
__global__ void k_conv(const float* __restrict__ wih, const float* __restrict__ whh,
                       const float* __restrict__ bih, const float* __restrict__ bhh,
                       f16* __restrict__ wih_h, uint* __restrict__ whh_t,
                       float* __restrict__ bias) {
  int i = blockIdx.x * 256 + threadIdx.x;   // 262144 threads
  wih_h[i] = (f16)wih[i];
  if (i < G4 * 128) {
    int row = i >> 7, p = i & 127;
    f16x2 v;
    v.x = (f16)whh[row * HID + 2 * p];
    v.y = (f16)whh[row * HID + 2 * p + 1];
    whh_t[p * G4 + row] = __builtin_bit_cast(uint, v);
  }
  if (i < G4) bias[i] = bih[i] + bhh[i];
}

// ---------------- K2: proj[n][dim][gate] = path[n]@W_ih^T + b (gate-packed epilogue)
#define BM 128
#define BN 128
#define BK 64
#define LPAD 72
__global__ __launch_bounds__(256) void k_gemm(const f16* __restrict__ A,
                                              const f16* __restrict__ Bw,
                                              const float* __restrict__ bias,
                                              f16* __restrict__ C) {
  __shared__ f16 sA[BM][LPAD];
  __shared__ f16 sB[BN][LPAD];
  int m0 = blockIdx.x * BM, n0 = blockIdx.y * BN;
  int tid = threadIdx.x;
  int wid = tid >> 6, lane = tid & 63;
  int wm = wid & 1, wn = wid >> 1;
  f32x4 acc[4][4] = {};
  for (int k0 = 0; k0 < 256; k0 += BK) {
    __syncthreads();
    int r = tid >> 3, kc = (tid & 7) * 8;
    for (int i = 0; i < 4; ++i) {
      int row = r + 32 * i;
      int gm = m0 + row;
      uint4 va = make_uint4(0u, 0u, 0u, 0u);
      if (gm < N_TYPES) va = *(const uint4*)&A[gm * 256 + k0 + kc];
      *(uint4*)&sA[row][kc] = va;
      uint4 vb = *(const uint4*)&Bw[(n0 + row) * 256 + k0 + kc];
      *(uint4*)&sB[row][kc] = vb;
    }
    __syncthreads();
#pragma unroll
    for (int ks = 0; ks < 2; ++ks) {
      f16x8 af[4], bf[4];
      int kk = ks * 32 + (lane >> 4) * 8;
#pragma unroll
      for (int mt = 0; mt < 4; ++mt)
        af[mt] = *(const f16x8*)&sA[wm * 64 + mt * 16 + (lane & 15)][kk];
#pragma unroll
      for (int nt = 0; nt < 4; ++nt)
        bf[nt] = *(const f16x8*)&sB[wn * 64 + nt * 16 + (lane & 15)][kk];
#pragma unroll
      for (int mt = 0; mt < 4; ++mt)
#pragma unroll
        for (int nt = 0; nt < 4; ++nt)
          acc[mt][nt] = __builtin_amdgcn_mfma_f32_16x16x32_f16(af[mt], bf[nt], acc[mt][nt], 0, 0, 0);
    }
  }
#pragma unroll
  for (int mt = 0; mt < 4; ++mt)
#pragma unroll
    for (int nt = 0; nt < 4; ++nt)
#pragma unroll
      for (int qq = 0; qq < 4; ++qq) {
        int row = m0 + wm * 64 + mt * 16 + (lane >> 4) * 4 + qq;
        int col = n0 + wn * 64 + nt * 16 + (lane & 15);
        int dim = col & 255, g = col >> 8;
        if (row < N_TYPES)
          C[row * G4 + dim * 4 + g] = (f16)(acc[mt][nt][qq] + bias[col]);
      }
}

// ---------------- K3: LSTM recurrence, v17 = R14 VERBATIM + amdgpu_waves_per_eu(2,2).
// R14 (1597us, tied-best): 256 WGs x 512 thr, bid=q*32+b; WG q owns dims [q*32,+32)
// x 4 gates = 128 rows, k-split over wave-pairs (kq=v>>1); tagged {f16x2,step} u64
// agent-relaxed fabric; polling on lanes 32..63 (role-clean vmcnt); single barrier;
// parity-double-buffered pl[2][4][128]; gate-packed proj x-prefetch.
//
// R16 post-mortem: barrier-free LDS flags = 1711 (null) -> all sync-side levers
// exhausted. Remaining leak: VGPR_Count=32 proves w[32] is DEMOTED; its L2 reloads
// are sunk after h-discovery and, with ~8 spare VGPRs, issue in ~4 serialized
// batches (~1000cy post-poll, every step). R1-R4's "residency is impossible"
// conclusion was confounded by the acquire-invalidation bug; R3->R4 proved
// amdgpu_waves_per_eu DOES move the allocation (76->132). Real occupancy is
// exactly 2 waves/SIMD (256 WGs / 256 CUs x 8 waves), so (2,2) is free and
// raises the RA budget to 256 VGPRs -> w[32] stays register-resident; matvec
// becomes pure VALU right after discovery.
__device__ __forceinline__ float dot2(uint wp, uint hp, float acc) {
#if __has_builtin(__builtin_amdgcn_fdot2)
  return __builtin_amdgcn_fdot2(__builtin_bit_cast(f16x2, wp),
                                __builtin_bit_cast(f16x2, hp), acc, false);
#else
  f16x2 a = __builtin_bit_cast(f16x2, wp);
  f16x2 b = __builtin_bit_cast(f16x2, hp);
  return acc + (float)a.x * (float)b.x + (float)a.y * (float)b.y;
#endif
}

__device__ __forceinline__ float sigm(float v) { return 1.f / (1.f + __expf(-v)); }
__device__ __forceinline__ float tanh_(float v) { return 1.f - 2.f / (__expf(2.f * v) + 1.f); }
__device__ __forceinline__ float f16u(ushort u) { return (float)__builtin_bit_cast(f16, u); }

__global__ __launch_bounds__(512)
__attribute__((amdgpu_waves_per_eu(2, 2)))
void k_lstm(const int* __restrict__ evs,
            const f16* __restrict__ proj,
            const uint* __restrict__ whh_t,
            u64* hglob,                 // [32 batch][2 slot][128 pair] tagged words
            float* __restrict__ out) {
  int bid = blockIdx.x;
  int b = bid & 31, q = bid >> 5;      // 8 WGs of batch b share bid%8 -> same XCD
  int t = threadIdx.x;
  int v = t >> 6, l = t & 63;
  int kq = v >> 1;                     // k-quarter, wave-uniform
  int rid = (v & 1) * 64 + l;          // local gate-row 0..127
  int rowg = (rid >> 5) * 256 + q * 32 + (rid & 31);   // global gate-row

  __shared__ float pl[2][4][128];      // partials [parity][kq][rid]

  uint w[32];                          // register-resident with waves_per_eu(2,2)
#pragma unroll
  for (int i = 0; i < 32; ++i) w[i] = whh_t[(kq * 32 + i) * G4 + rowg];

  u64* hb = hglob + b * 256;           // [2][128]
  const int* ev = evs + b * SEQ;

  // t<32 carries x (4 gates, gate-packed) one step ahead; these lanes never poll.
  float x0 = 0.f, x1 = 0.f, x2 = 0.f, x3 = 0.f;
  if (t < 32) {
    ushort4 xv = *(const ushort4*)(proj + (long)ev[0] * G4 + (q * 32 + t) * 4);
    x0 = f16u(xv.x); x1 = f16u(xv.y); x2 = f16u(xv.z); x3 = f16u(xv.w);
  }

  float c = 0.f;

  for (int step = 0; step < SEQ; ++step) {
    // (1) poll h_{step-1}: lanes 32..63 of every wave (clean vmcnt: no stores here)
    int h0 = 0;
    if (step > 0 && l >= 32) {
      const u64* src = hb + ((step - 1) & 1) * 128 + kq * 32 + (l - 32);
      u64 val;
      do {
        val = __hip_atomic_load(src, __ATOMIC_RELAXED, __HIP_MEMORY_SCOPE_AGENT);
      } while ((uint)(val >> 32) != (uint)step);
      h0 = (int)(uint)val;
    }

    // (2) matvec partial over pairs [kq*32,+32): readlane sources are lanes 32..63
    float a0 = 0.f, a1 = 0.f, a2 = 0.f, a3 = 0.f;
#pragma unroll
    for (int i = 0; i < 32; i += 4) {
      a0 = dot2(w[i + 0], (uint)__builtin_amdgcn_readlane(h0, 32 + i + 0), a0);
      a1 = dot2(w[i + 1], (uint)__builtin_amdgcn_readlane(h0, 32 + i + 1), a1);
      a2 = dot2(w[i + 2], (uint)__builtin_amdgcn_readlane(h0, 32 + i + 2), a2);
      a3 = dot2(w[i + 3], (uint)__builtin_amdgcn_readlane(h0, 32 + i + 3), a3);
    }
    pl[step & 1][kq][rid] = (a0 + a1) + (a2 + a3);   // lanes stride-1: conflict-free

    __syncthreads();                   // the only barrier per step

    // (3) finale on t<32: 16 pl reads + x + activations + publish + out + x-prefetch
    if (t < 32) {
      const float (*pp)[128] = pl[step & 1];
      float s0 = (pp[0][t]      + pp[1][t])      + (pp[2][t]      + pp[3][t])      + x0;
      float s1 = (pp[0][32 + t] + pp[1][32 + t]) + (pp[2][32 + t] + pp[3][32 + t]) + x1;
      float s2 = (pp[0][64 + t] + pp[1][64 + t]) + (pp[2][64 + t] + pp[3][64 + t]) + x2;
      float s3 = (pp[0][96 + t] + pp[1][96 + t]) + (pp[2][96 + t] + pp[3][96 + t]) + x3;
      float iv = sigm(s0), fv = sigm(s1), gv = tanh_(s2), ov = sigm(s3);
      c = fv * c + iv * gv;
      float hval = ov * tanh_(c);
      float hA = __shfl(hval, 2 * (t & 15));
      float hB = __shfl(hval, 2 * (t & 15) + 1);
      if (t < 16) {                    // publish FIRST (critical path)
        f16x2 pk; pk.x = (f16)hA; pk.y = (f16)hB;
        uint pku = __builtin_bit_cast(uint, pk);
        u64 val = (u64)pku | ((u64)(uint)(step + 1) << 32);
        __hip_atomic_store(hb + (step & 1) * 128 + q * 16 + t, val,
                           __ATOMIC_RELAXED, __HIP_MEMORY_SCOPE_AGENT);
      }
      out[(step * BATCH + b) * HID + q * 32 + t] = hval;   // off the sync path
      if (step + 1 < SEQ) {            // x-prefetch, full step of slack
        ushort4 xv = *(const ushort4*)(proj + (long)ev[step + 1] * G4 + (q * 32 + t) * 4);
        x0 = f16u(xv.x); x1 = f16u(xv.y); x2 = f16u(xv.z); x3 = f16u(xv.w);
      }
    }
    // hazards: reads of pl[s&1] (finale s) complete before that thread reaches
    // barrier(s+1); next write of pl[s&1] is in step s+2, after barrier(s+1). Safe.
    // hb slot reuse: R5-proven publish-order argument.
  }
}

extern "C" void kernel_launch(void* const* d_in, const int* in_sizes, int n_in,
                              void* d_out, int out_size, void* d_ws, size_t ws_size,
                              hipStream_t stream) {
  (void)n_in; (void)out_size; (void)ws_size;
  const int* evs = (const int*)d_in[0];
  const int* anc = (const int*)d_in[1];
  const float* weight = (const float*)d_in[2];
  const float* emb = (const float*)d_in[3];
  const float* wih = (const float*)d_in[4];
  const float* whh = (const float*)d_in[5];
  const float* bih = (const float*)d_in[6];
  const float* bhh = (const float*)d_in[7];
  int D = in_sizes[1] / N_TYPES;

  char* ws = (char*)d_ws;
  f16* path = (f16*)(ws);                       // 10000*256*2 = 5,120,000 (dead after k_gemm)
  f16* wih_h = (f16*)(ws + 5242880);            // 524,288
  uint* whh_t = (uint*)(ws + 5767168);          // 524,288
  float* bias = (float*)(ws + 6291456);         // 4,096
  f16* proj = (f16*)(ws + 6295552);             // 10000*1024*2 = 20,480,000 (gate-packed)
  u64* hglob = (u64*)(ws + 26775552);           // 32*2*128*8 = 65,536
  float* out = (float*)d_out;

  k_conv<<<1024, 256, 0, stream>>>(wih, whh, bih, bhh, wih_h, whh_t, bias);
  k_path<<<N_TYPES, 256, 0, stream>>>(anc, weight, emb, D, path);
  k_gemm<<<dim3(79, 8), 256, 0, stream>>>(path, wih_h, bias, proj);
  hipMemsetAsync(hglob, 0, 32 * 2 * 128 * 8, stream);   // zero tags (replay-safe)
  k_lstm<<<256, 512, 0, stream>>>(evs, proj, whh_t, hglob, out);
}